// Round 2
// baseline (1159.419 us; speedup 1.0000x reference)
//
#include <hip/hip_runtime.h>

#define L_SEQ 2048
#define BATCH 16
#define DIN   512
#define NOUT  1536                    // 3*D_OUT
#define MROWS (L_SEQ*BATCH)           // 32768
#define PROWS ((L_SEQ+2)*BATCH)       // 32800 padded rows (one zero l at each end)

typedef short  short8  __attribute__((ext_vector_type(8)));
typedef float  f32x4   __attribute__((ext_vector_type(4)));
typedef unsigned short ushort8v __attribute__((ext_vector_type(8)));

static __device__ __forceinline__ unsigned short f2bf(float v) {
  unsigned u = __float_as_uint(v);
  u += 0x7FFFu + ((u >> 16) & 1u);      // RNE
  return (unsigned short)(u >> 16);
}
static __device__ __forceinline__ float bf2f(unsigned short s) {
  return __uint_as_float(((unsigned)s) << 16);
}
static __device__ __forceinline__ float sigm(float x) { return 1.f / (1.f + __expf(-x)); }
static __device__ __forceinline__ float tanh_f(float x) {
  float ax = fabsf(x);
  float t = __expf(-2.f * ax);
  float r = (1.f - t) / (1.f + t);
  return x < 0.f ? -r : r;
}

// ---------------- prep: pad + hi/lo split of x ----------------
// x_pad row pr = (l+1)*16 + b ; rows l=-1 and l=2048 are zeros.
__global__ __launch_bounds__(256) void prep_x(const float* __restrict__ x,
                                              unsigned short* __restrict__ xh,
                                              unsigned short* __restrict__ xl) {
  int gid = blockIdx.x * 256 + threadIdx.x;       // 2050*16*64 = 2,099,200 threads
  int pr = gid >> 6, seg = gid & 63;
  int l = (pr >> 4) - 1;
  ushort8v h = (ushort8v)0, lo = (ushort8v)0;
  if (l >= 0 && l < L_SEQ) {
    const float* src = x + (size_t)(pr - 16) * DIN + seg * 8;
#pragma unroll
    for (int i = 0; i < 8; ++i) {
      float v = src[i];
      unsigned short hb = f2bf(v);
      h[i] = hb;
      lo[i] = f2bf(v - bf2f(hb));
    }
  }
  *(ushort8v*)(xh + (size_t)gid * 8) = h;
  *(ushort8v*)(xl + (size_t)gid * 8) = lo;
}

// ---------------- prep: transpose W [k][d][e] -> wT [k][e][d], hi/lo split ----------------
__global__ __launch_bounds__(256) void prep_w(const float* __restrict__ Wf, const float* __restrict__ Wr,
                                              unsigned short* __restrict__ wThf, unsigned short* __restrict__ wTlf,
                                              unsigned short* __restrict__ wThr, unsigned short* __restrict__ wTlr) {
  __shared__ float tile[32][33];
  int bid = blockIdx.x;                 // 2 dirs * 3 k * 16 dtiles * 48 etiles = 4608
  int dir = bid & 1; bid >>= 1;
  int et = bid % 48; bid /= 48;
  int dt = bid % 16; int k = bid / 16;
  const float* W = dir ? Wr : Wf;
  unsigned short* th = dir ? wThr : wThf;
  unsigned short* tl = dir ? wTlr : wTlf;
  int tx = threadIdx.x & 31, ty = threadIdx.x >> 5;
  int d0 = dt * 32, e0 = et * 32;
  const float* Wk = W + (size_t)k * DIN * NOUT;
#pragma unroll
  for (int r = 0; r < 4; ++r)
    tile[ty + r * 8][tx] = Wk[(size_t)(d0 + ty + r * 8) * NOUT + e0 + tx];
  __syncthreads();
#pragma unroll
  for (int r = 0; r < 4; ++r) {
    int e = e0 + ty + r * 8;
    float v = tile[tx][ty + r * 8];
    unsigned short hb = f2bf(v);
    size_t o = (size_t)k * NOUT * DIN + (size_t)e * DIN + d0 + tx;
    th[o] = hb;
    tl[o] = f2bf(v - bf2f(hb));
  }
}

// ---------------- gates GEMM: g = sum_k xpad(+16k) * wT[k] + masked bias ----------------
static __device__ __forceinline__ void gload16(const void* g, void* l) {
  __builtin_amdgcn_global_load_lds((const __attribute__((address_space(1))) void*)g,
                                   (__attribute__((address_space(3))) void*)l, 16, 0, 0);
}

__global__ __launch_bounds__(256) void gemm_gates(
    const short* __restrict__ xh, const short* __restrict__ xl,      // [PROWS][512] bf16 bits
    const short* __restrict__ wTh, const short* __restrict__ wTl,    // [3][1536][512] bf16 bits
    const float* __restrict__ bias,                                  // [3][1536]
    float* __restrict__ g)                                           // [32768][1536]
{
  __shared__ short Ah[128 * 32], Al[128 * 32], Bh[128 * 32], Bl[128 * 32];
  const int tid = threadIdx.x;
  const int wave = tid >> 6, lane = tid & 63;
  const int mt = blockIdx.x & 255, nt = blockIdx.x >> 8;
  const int brow = mt * 128, bcol = nt * 128;

  const int aw_row = lane >> 2;              // 16 rows per wave-call (4 lanes/row)
  const int aw_col = (lane & 3) * 8;         // 8 bf16 = 16B per lane

  f32x4 acc[4][4];
#pragma unroll
  for (int i = 0; i < 4; ++i)
#pragma unroll
    for (int j = 0; j < 4; ++j) acc[i][j] = (f32x4)(0.f);

  const int wm = (wave >> 1) * 64, wn = (wave & 1) * 64;
  const int fr = lane & 15;
  const int fko = (lane >> 4) * 8;

  for (int k = 0; k < 3; ++k) {
    const short* xsh = xh + (size_t)(brow + 16 * k) * DIN;
    const short* xsl = xl + (size_t)(brow + 16 * k) * DIN;
    const short* wsh = wTh + (size_t)k * NOUT * DIN + (size_t)bcol * DIN;
    const short* wsl = wTl + (size_t)k * NOUT * DIN + (size_t)bcol * DIN;
    for (int kk = 0; kk < DIN; kk += 32) {
#pragma unroll
      for (int c = 0; c < 2; ++c) {
        int row = wave * 32 + c * 16 + aw_row;          // 0..127
        int ldst = (wave * 32 + c * 16) * 32;           // LDS elem offset (row*32)
        int aoff = row * DIN + kk + aw_col;
        gload16(xsh + aoff, Ah + ldst);
        gload16(xsl + aoff, Al + ldst);
        int boff = row * DIN + kk + aw_col;             // row is e-index for B
        gload16(wsh + boff, Bh + ldst);
        gload16(wsl + boff, Bl + ldst);
      }
      __syncthreads();
      short8 a_h[4], a_l[4], b_h[4], b_l[4];
#pragma unroll
      for (int i = 0; i < 4; ++i) {
        a_h[i] = *(const short8*)(Ah + (wm + i * 16 + fr) * 32 + fko);
        a_l[i] = *(const short8*)(Al + (wm + i * 16 + fr) * 32 + fko);
        b_h[i] = *(const short8*)(Bh + (wn + i * 16 + fr) * 32 + fko);
        b_l[i] = *(const short8*)(Bl + (wn + i * 16 + fr) * 32 + fko);
      }
#pragma unroll
      for (int i = 0; i < 4; ++i)
#pragma unroll
        for (int j = 0; j < 4; ++j) {
          acc[i][j] = __builtin_amdgcn_mfma_f32_16x16x32_bf16(a_h[i], b_h[j], acc[i][j], 0, 0, 0);
          acc[i][j] = __builtin_amdgcn_mfma_f32_16x16x32_bf16(a_h[i], b_l[j], acc[i][j], 0, 0, 0);
          acc[i][j] = __builtin_amdgcn_mfma_f32_16x16x32_bf16(a_l[i], b_h[j], acc[i][j], 0, 0, 0);
        }
      __syncthreads();
    }
  }
  // epilogue: add masked bias, store f32
  const float* b0 = bias;
  const float* b1 = bias + NOUT;
  const float* b2 = bias + 2 * NOUT;
#pragma unroll
  for (int j = 0; j < 4; ++j) {
    int gcol = bcol + wn + j * 16 + fr;
    float bb0 = b0[gcol], bb1 = b1[gcol], bb2 = b2[gcol];
#pragma unroll
    for (int i = 0; i < 4; ++i) {
#pragma unroll
      for (int q = 0; q < 4; ++q) {
        int grow = brow + wm + i * 16 + (lane >> 4) * 4 + q;
        int l = grow >> 4;                      // B == 16
        float bs = bb1 + (l > 0 ? bb0 : 0.f) + (l < L_SEQ - 1 ? bb2 : 0.f);
        g[(size_t)grow * NOUT + gcol] = acc[i][j][q] + bs;
      }
    }
  }
}

// ---------------- fo-pool: 3-phase chunked linear scan ----------------
// 32 chunks of 64 steps; series idx = b*512 + j (8192 series per direction)
__global__ __launch_bounds__(256) void pool_phase1(const float* __restrict__ g,
                                                   float* __restrict__ Aarr, float* __restrict__ Bvarr,
                                                   int rev) {
  int gid = blockIdx.x * 256 + threadIdx.x;       // 32*8192
  int q = gid >> 13, idx = gid & 8191;
  int b = idx >> 9, j = idx & 511;
  const float* gf = g + (size_t)b * NOUT + j;
  float A = 1.f, Bv = 0.f;
  int l0 = q * 64;
#pragma unroll 4
  for (int t = 0; t < 64; ++t) {
    int l = rev ? (l0 + 63 - t) : (l0 + t);
    size_t off = (size_t)l * (BATCH * NOUT);
    float f = sigm(gf[off]);
    float z = tanh_f(gf[off + 1024]);
    Bv = f * z + (1.f - f) * Bv;
    A *= (1.f - f);
  }
  Aarr[gid] = A;
  Bvarr[gid] = Bv;
}

__global__ __launch_bounds__(256) void pool_phase2(const float* __restrict__ Aarr,
                                                   const float* __restrict__ Bvarr,
                                                   float* __restrict__ Cin, int rev) {
  int idx = blockIdx.x * 256 + threadIdx.x;       // 8192
  float c = 0.f;
  for (int s = 0; s < 32; ++s) {
    int q = rev ? 31 - s : s;
    size_t o = (size_t)q * 8192 + idx;
    Cin[o] = c;
    c = Aarr[o] * c + Bvarr[o];
  }
}

__global__ __launch_bounds__(256) void pool_phase3(const float* __restrict__ g,
                                                   const float* __restrict__ Cin,
                                                   float* __restrict__ out,
                                                   float* __restrict__ lh, float* __restrict__ lc,
                                                   int rev) {
  int gid = blockIdx.x * 256 + threadIdx.x;       // 32*8192
  int q = gid >> 13, idx = gid & 8191;
  int b = idx >> 9, j = idx & 511;
  const float* gf = g + (size_t)b * NOUT + j;
  float c = Cin[gid];
  int l0 = q * 64;
#pragma unroll 2
  for (int t = 0; t < 64; ++t) {
    int l = rev ? (l0 + 63 - t) : (l0 + t);
    size_t off = (size_t)l * (BATCH * NOUT);
    float f = sigm(gf[off]);
    float o = sigm(gf[off + 512]);
    float z = tanh_f(gf[off + 1024]);
    c = f * z + (1.f - f) * c;
    float h = c * o;
    out[(size_t)(l * BATCH + b) * 1024 + rev * 512 + j] = h;
    if (l == L_SEQ - 1) {             // fwd: last step of last chunk; rev: first step of chunk 31
      lh[b * 1024 + rev * 512 + j] = h;
      lc[b * 1024 + rev * 512 + j] = c;
    }
  }
}

// ---------------- launch ----------------
extern "C" void kernel_launch(void* const* d_in, const int* in_sizes, int n_in,
                              void* d_out, int out_size, void* d_ws, size_t ws_size,
                              hipStream_t stream) {
  const float* x    = (const float*)d_in[0];
  const float* fwdW = (const float*)d_in[2];
  const float* fwdb = (const float*)d_in[3];
  const float* revW = (const float*)d_in[4];
  const float* revb = (const float*)d_in[5];

  float* out = (float*)d_out;
  float* lh  = out + (size_t)L_SEQ * BATCH * 1024;
  float* lc  = lh + BATCH * 1024;

  char* ws = (char*)d_ws;
  size_t off = 0;
  float* g = (float*)(ws + off);              off += (size_t)MROWS * NOUT * 4;   // 192 MB
  unsigned short* xhp = (unsigned short*)(ws + off); off += (size_t)PROWS * DIN * 2;
  unsigned short* xlp = (unsigned short*)(ws + off); off += (size_t)PROWS * DIN * 2;
  unsigned short* wThf = (unsigned short*)(ws + off); off += (size_t)3 * NOUT * DIN * 2;
  unsigned short* wTlf = (unsigned short*)(ws + off); off += (size_t)3 * NOUT * DIN * 2;
  unsigned short* wThr = (unsigned short*)(ws + off); off += (size_t)3 * NOUT * DIN * 2;
  unsigned short* wTlr = (unsigned short*)(ws + off); off += (size_t)3 * NOUT * DIN * 2;
  float* Aarr  = (float*)(ws + off); off += (size_t)32 * 8192 * 4;
  float* Bvarr = (float*)(ws + off); off += (size_t)32 * 8192 * 4;
  float* Cin   = (float*)(ws + off); off += (size_t)32 * 8192 * 4;

  prep_x<<<8200, 256, 0, stream>>>(x, xhp, xlp);
  prep_w<<<4608, 256, 0, stream>>>(fwdW, revW, wThf, wTlf, wThr, wTlr);

  for (int dir = 0; dir < 2; ++dir) {
    const unsigned short* wh = dir ? wThr : wThf;
    const unsigned short* wl = dir ? wTlr : wTlf;
    const float* bias = dir ? revb : fwdb;
    gemm_gates<<<256 * 12, 256, 0, stream>>>((const short*)xhp, (const short*)xlp,
                                             (const short*)wh, (const short*)wl, bias, g);
    pool_phase1<<<1024, 256, 0, stream>>>(g, Aarr, Bvarr, dir);
    pool_phase2<<<32, 256, 0, stream>>>(Aarr, Bvarr, Cin, dir);
    pool_phase3<<<1024, 256, 0, stream>>>(g, Cin, out, lh, lc, dir);
  }
}

// Round 5
// 695.920 us; speedup vs baseline: 1.6660x; 1.6660x over previous
//
#include <hip/hip_runtime.h>

#define L_SEQ 2048
#define BATCH 16
#define DIN   512
#define NOUT  1536                    // 3*D_OUT
#define MROWS (L_SEQ*BATCH)           // 32768
#define PROWS ((L_SEQ+2)*BATCH)       // 32800 padded rows (one zero l at each end)

typedef float    f32x4 __attribute__((ext_vector_type(4)));
typedef _Float16 half8 __attribute__((ext_vector_type(8)));

static __device__ __forceinline__ float sigm(float x) { return 1.f / (1.f + __expf(-x)); }
static __device__ __forceinline__ float tanh_f(float x) {
  float ax = fabsf(x);
  float t = __expf(-2.f * ax);
  float r = (1.f - t) / (1.f + t);
  return x < 0.f ? -r : r;
}

// ---------------- prep: pad + fp16 convert of x ----------------
// x_pad row pr = (l+1)*16 + b ; rows l=-1 and l=2048 are zeros.
__global__ __launch_bounds__(256) void prep_x(const float* __restrict__ x,
                                              _Float16* __restrict__ xh) {
  int gid = blockIdx.x * 256 + threadIdx.x;       // 32800*64 = 2,099,200 threads
  int pr = gid >> 6, seg = gid & 63;
  int l = (pr >> 4) - 1;
  half8 h = (half8)0;
  if (l >= 0 && l < L_SEQ) {
    const float* src = x + (size_t)(pr - 16) * DIN + seg * 8;
#pragma unroll
    for (int i = 0; i < 8; ++i) h[i] = (_Float16)src[i];   // v_cvt_f16_f32, RNE
  }
  *(half8*)(xh + (size_t)gid * 8) = h;
}

// ---------------- prep: transpose W [k][d][e] -> wT [k][e][d], fp16 ----------------
__global__ __launch_bounds__(256) void prep_w(const float* __restrict__ Wf, const float* __restrict__ Wr,
                                              _Float16* __restrict__ wTf, _Float16* __restrict__ wTr) {
  __shared__ float tile[32][33];
  int bid = blockIdx.x;                 // 2 dirs * 3 k * 16 dtiles * 48 etiles = 4608
  int dir = bid & 1; bid >>= 1;
  int et = bid % 48; bid /= 48;
  int dt = bid % 16; int k = bid / 16;
  const float* W = dir ? Wr : Wf;
  _Float16* th = dir ? wTr : wTf;
  int tx = threadIdx.x & 31, ty = threadIdx.x >> 5;
  int d0 = dt * 32, e0 = et * 32;
  const float* Wk = W + (size_t)k * DIN * NOUT;
#pragma unroll
  for (int r = 0; r < 4; ++r)
    tile[ty + r * 8][tx] = Wk[(size_t)(d0 + ty + r * 8) * NOUT + e0 + tx];
  __syncthreads();
#pragma unroll
  for (int r = 0; r < 4; ++r) {
    int e = e0 + ty + r * 8;
    size_t o = (size_t)k * NOUT * DIN + (size_t)e * DIN + d0 + tx;
    th[o] = (_Float16)tile[tx][ty + r * 8];
  }
}

// ---------------- gates GEMM: g = sum_k xpad(+16k) * wT[k] + masked bias ----------------
static __device__ __forceinline__ void gload16(const void* g, void* l) {
  __builtin_amdgcn_global_load_lds((const __attribute__((address_space(1))) void*)g,
                                   (__attribute__((address_space(3))) void*)l, 16, 0, 0);
}

__global__ __launch_bounds__(256) void gemm_gates(
    const _Float16* __restrict__ xh,        // [PROWS][512]
    const _Float16* __restrict__ wTh,       // [3][1536][512]
    const float* __restrict__ bias,         // [3][1536]
    float* __restrict__ g)                  // [32768][1536]
{
  __shared__ _Float16 Ah[128 * 32], Bh[128 * 32];          // 16 KB total
  const int tid = threadIdx.x;
  const int wave = tid >> 6, lane = tid & 63;
  int bid = blockIdx.x;                                    // 3072 = 8*384
  bid = (bid & 7) * 384 + (bid >> 3);                      // XCD-aware swizzle (bijective)
  const int mt = bid & 255, nt = bid >> 8;
  const int brow = mt * 128, bcol = nt * 128;

  // staging: lane covers (row_rel = lane>>2, slot = lane&3); source slot XOR-swizzled
  const int aw_row = lane >> 2;
  const int aw_col = ((lane & 3) ^ ((lane >> 3) & 3)) * 8;   // pre-swizzled global source

  f32x4 acc[4][4];
#pragma unroll
  for (int i = 0; i < 4; ++i)
#pragma unroll
    for (int j = 0; j < 4; ++j) acc[i][j] = (f32x4)(0.f);

  const int wm = (wave >> 1) * 64, wn = (wave & 1) * 64;
  const int fr = lane & 15;
  const int fko = (((lane >> 4) ^ ((fr >> 1) & 3))) * 8;     // XOR-swizzled read slot

  for (int k = 0; k < 3; ++k) {
    const _Float16* xs = xh + (size_t)(brow + 16 * k) * DIN;
    const _Float16* ws = wTh + (size_t)k * NOUT * DIN + (size_t)bcol * DIN;
    for (int kk = 0; kk < DIN; kk += 32) {
#pragma unroll
      for (int c = 0; c < 2; ++c) {
        int row = wave * 32 + c * 16 + aw_row;          // 0..127
        int ldst = (wave * 32 + c * 16) * 32;           // LDS half-elem offset (linear dest)
        gload16(xs + (size_t)row * DIN + kk + aw_col, Ah + ldst);
        gload16(ws + (size_t)row * DIN + kk + aw_col, Bh + ldst);
      }
      __syncthreads();
      half8 a[4], b[4];
#pragma unroll
      for (int i = 0; i < 4; ++i) {
        a[i] = *(const half8*)(Ah + (wm + i * 16 + fr) * 32 + fko);
        b[i] = *(const half8*)(Bh + (wn + i * 16 + fr) * 32 + fko);
      }
#pragma unroll
      for (int i = 0; i < 4; ++i)
#pragma unroll
        for (int j = 0; j < 4; ++j)
          acc[i][j] = __builtin_amdgcn_mfma_f32_16x16x32_f16(a[i], b[j], acc[i][j], 0, 0, 0);
      __syncthreads();
    }
  }
  // epilogue: add masked bias, store f32
  const float* b0 = bias;
  const float* b1 = bias + NOUT;
  const float* b2 = bias + 2 * NOUT;
#pragma unroll
  for (int j = 0; j < 4; ++j) {
    int gcol = bcol + wn + j * 16 + fr;
    float bb0 = b0[gcol], bb1 = b1[gcol], bb2 = b2[gcol];
#pragma unroll
    for (int i = 0; i < 4; ++i) {
#pragma unroll
      for (int q = 0; q < 4; ++q) {
        int grow = brow + wm + i * 16 + (lane >> 4) * 4 + q;
        int l = grow >> 4;                      // B == 16
        float bs = bb1 + (l > 0 ? bb0 : 0.f) + (l < L_SEQ - 1 ? bb2 : 0.f);
        g[(size_t)grow * NOUT + gcol] = acc[i][j][q] + bs;
      }
    }
  }
}

// ---------------- fo-pool: 3-phase chunked linear scan ----------------
// 32 chunks of 64 steps; series idx = b*512 + j (8192 series per direction)
__global__ __launch_bounds__(256) void pool_phase1(const float* __restrict__ g,
                                                   float* __restrict__ Aarr, float* __restrict__ Bvarr,
                                                   int rev) {
  int gid = blockIdx.x * 256 + threadIdx.x;       // 32*8192
  int q = gid >> 13, idx = gid & 8191;
  int b = idx >> 9, j = idx & 511;
  const float* gf = g + (size_t)b * NOUT + j;
  float A = 1.f, Bv = 0.f;
  int l0 = q * 64;
#pragma unroll 4
  for (int t = 0; t < 64; ++t) {
    int l = rev ? (l0 + 63 - t) : (l0 + t);
    size_t off = (size_t)l * (BATCH * NOUT);
    float f = sigm(gf[off]);
    float z = tanh_f(gf[off + 1024]);
    Bv = f * z + (1.f - f) * Bv;
    A *= (1.f - f);
  }
  Aarr[gid] = A;
  Bvarr[gid] = Bv;
}

__global__ __launch_bounds__(256) void pool_phase2(const float* __restrict__ Aarr,
                                                   const float* __restrict__ Bvarr,
                                                   float* __restrict__ Cin, int rev) {
  int idx = blockIdx.x * 256 + threadIdx.x;       // 8192
  float c = 0.f;
  for (int s = 0; s < 32; ++s) {
    int q = rev ? 31 - s : s;
    size_t o = (size_t)q * 8192 + idx;
    Cin[o] = c;
    c = Aarr[o] * c + Bvarr[o];
  }
}

__global__ __launch_bounds__(256) void pool_phase3(const float* __restrict__ g,
                                                   const float* __restrict__ Cin,
                                                   float* __restrict__ out,
                                                   float* __restrict__ lh, float* __restrict__ lc,
                                                   int rev) {
  int gid = blockIdx.x * 256 + threadIdx.x;       // 32*8192
  int q = gid >> 13, idx = gid & 8191;
  int b = idx >> 9, j = idx & 511;
  const float* gf = g + (size_t)b * NOUT + j;
  float c = Cin[gid];
  int l0 = q * 64;
#pragma unroll 2
  for (int t = 0; t < 64; ++t) {
    int l = rev ? (l0 + 63 - t) : (l0 + t);
    size_t off = (size_t)l * (BATCH * NOUT);
    float f = sigm(gf[off]);
    float o = sigm(gf[off + 512]);
    float z = tanh_f(gf[off + 1024]);
    c = f * z + (1.f - f) * c;
    float h = c * o;
    out[(size_t)(l * BATCH + b) * 1024 + rev * 512 + j] = h;
    if (l == L_SEQ - 1) {             // fwd: last step of last chunk; rev: first step of chunk 31
      lh[b * 1024 + rev * 512 + j] = h;
      lc[b * 1024 + rev * 512 + j] = c;
    }
  }
}

// ---------------- launch ----------------
extern "C" void kernel_launch(void* const* d_in, const int* in_sizes, int n_in,
                              void* d_out, int out_size, void* d_ws, size_t ws_size,
                              hipStream_t stream) {
  const float* x    = (const float*)d_in[0];
  const float* fwdW = (const float*)d_in[2];
  const float* fwdb = (const float*)d_in[3];
  const float* revW = (const float*)d_in[4];
  const float* revb = (const float*)d_in[5];

  float* out = (float*)d_out;
  float* lh  = out + (size_t)L_SEQ * BATCH * 1024;
  float* lc  = lh + BATCH * 1024;

  char* ws = (char*)d_ws;
  size_t off = 0;
  float* g = (float*)(ws + off);              off += (size_t)MROWS * NOUT * 4;   // 192 MB
  _Float16* xhp = (_Float16*)(ws + off);      off += (size_t)PROWS * DIN * 2;    // 33.6 MB
  _Float16* wTf = (_Float16*)(ws + off);      off += (size_t)3 * NOUT * DIN * 2; // 4.7 MB
  _Float16* wTr = (_Float16*)(ws + off);      off += (size_t)3 * NOUT * DIN * 2;
  float* Aarr  = (float*)(ws + off); off += (size_t)32 * 8192 * 4;
  float* Bvarr = (float*)(ws + off); off += (size_t)32 * 8192 * 4;
  float* Cin   = (float*)(ws + off); off += (size_t)32 * 8192 * 4;

  prep_x<<<8200, 256, 0, stream>>>(x, xhp);
  prep_w<<<4608, 256, 0, stream>>>(fwdW, revW, wTf, wTr);

  for (int dir = 0; dir < 2; ++dir) {
    const _Float16* wh = dir ? wTr : wTf;
    const float* bias = dir ? revb : fwdb;
    gemm_gates<<<3072, 256, 0, stream>>>(xhp, wh, bias, g);
    pool_phase1<<<1024, 256, 0, stream>>>(g, Aarr, Bvarr, dir);
    pool_phase2<<<32, 256, 0, stream>>>(Aarr, Bvarr, Cin, dir);
    pool_phase3<<<1024, 256, 0, stream>>>(g, Cin, out, lh, lc, dir);
  }
}

// Round 6
// 662.353 us; speedup vs baseline: 1.7505x; 1.0507x over previous
//
#include <hip/hip_runtime.h>

#define L_SEQ 2048
#define BATCH 16
#define DIN   512
#define NOUT  1536                    // 3*D_OUT
#define MROWS (L_SEQ*BATCH)           // 32768
#define PROWS ((L_SEQ+2)*BATCH)       // 32800 padded rows (one zero l at each end)
#define NTILES 48                     // 3 taps * 16 kk-steps of 32

typedef float    f32x4 __attribute__((ext_vector_type(4)));
typedef _Float16 half8 __attribute__((ext_vector_type(8)));

static __device__ __forceinline__ float sigm(float x) { return 1.f / (1.f + __expf(-x)); }
static __device__ __forceinline__ float tanh_f(float x) {
  float ax = fabsf(x);
  float t = __expf(-2.f * ax);
  float r = (1.f - t) / (1.f + t);
  return x < 0.f ? -r : r;
}

// ---------------- prep: pad + fp16 convert of x ----------------
__global__ __launch_bounds__(256) void prep_x(const float* __restrict__ x,
                                              _Float16* __restrict__ xh) {
  int gid = blockIdx.x * 256 + threadIdx.x;       // 32800*64 = 2,099,200 threads
  int pr = gid >> 6, seg = gid & 63;
  int l = (pr >> 4) - 1;
  half8 h = (half8)0;
  if (l >= 0 && l < L_SEQ) {
    const float* src = x + (size_t)(pr - 16) * DIN + seg * 8;
#pragma unroll
    for (int i = 0; i < 8; ++i) h[i] = (_Float16)src[i];
  }
  *(half8*)(xh + (size_t)gid * 8) = h;
}

// ---------------- prep: transpose W [k][d][e] -> wT [k][e][d], fp16 ----------------
__global__ __launch_bounds__(256) void prep_w(const float* __restrict__ Wf, const float* __restrict__ Wr,
                                              _Float16* __restrict__ wTf, _Float16* __restrict__ wTr) {
  __shared__ float tile[32][33];
  int bid = blockIdx.x;                 // 2 dirs * 3 k * 16 dtiles * 48 etiles = 4608
  int dir = bid & 1; bid >>= 1;
  int et = bid % 48; bid /= 48;
  int dt = bid % 16; int k = bid / 16;
  const float* W = dir ? Wr : Wf;
  _Float16* th = dir ? wTr : wTf;
  int tx = threadIdx.x & 31, ty = threadIdx.x >> 5;
  int d0 = dt * 32, e0 = et * 32;
  const float* Wk = W + (size_t)k * DIN * NOUT;
#pragma unroll
  for (int r = 0; r < 4; ++r)
    tile[ty + r * 8][tx] = Wk[(size_t)(d0 + ty + r * 8) * NOUT + e0 + tx];
  __syncthreads();
#pragma unroll
  for (int r = 0; r < 4; ++r) {
    int e = e0 + ty + r * 8;
    size_t o = (size_t)k * NOUT * DIN + (size_t)e * DIN + d0 + tx;
    th[o] = (_Float16)tile[tx][ty + r * 8];
  }
}

// ---------------- gates GEMM: 2-deep counted-vmcnt pipeline ----------------
static __device__ __forceinline__ void gload16(const void* g, void* l) {
  __builtin_amdgcn_global_load_lds((const __attribute__((address_space(1))) void*)g,
                                   (__attribute__((address_space(3))) void*)l, 16, 0, 0);
}

__global__ __launch_bounds__(256) void gemm_gates(
    const _Float16* __restrict__ xh,        // [PROWS][512]
    const _Float16* __restrict__ wTh,       // [3][1536][512]
    const float* __restrict__ bias,         // [3][1536]
    float* __restrict__ g)                  // [32768][1536]
{
  // LDS: A buf0 @0, A buf1 @4096, B buf0 @8192, B buf1 @12288 (half elems) = 32 KB
  __shared__ _Float16 AB[4 * 4096];
  const int tid = threadIdx.x;
  const int wave = tid >> 6, lane = tid & 63;
  int bid = blockIdx.x;                                    // 3072 = 8*384
  bid = (bid & 7) * 384 + (bid >> 3);                      // XCD-aware swizzle (bijective)
  const int mt = bid & 255, nt = bid >> 8;
  const int brow = mt * 128, bcol = nt * 128;

  const int aw_row = lane >> 2;
  const int aw_col = ((lane & 3) ^ ((lane >> 3) & 3)) * 8;   // pre-swizzled global source

  const _Float16* xbase = xh + (size_t)brow * DIN;           // tap k adds 16*k rows
  const _Float16* wbase = wTh + (size_t)bcol * DIN;          // tap k adds k*NOUT*DIN

  f32x4 acc[4][4];
#pragma unroll
  for (int i = 0; i < 4; ++i)
#pragma unroll
    for (int j = 0; j < 4; ++j) acc[i][j] = (f32x4)(0.f);

  const int wm = (wave >> 1) * 64, wn = (wave & 1) * 64;
  const int fr = lane & 15;
  const int fko = (((lane >> 4) ^ ((fr >> 1) & 3))) * 8;     // XOR-swizzled read slot

  // stage tile t into buffer buf (4 global_load_lds per thread)
  auto stage = [&](int t, int buf) {
    int k = t >> 4, kk = (t & 15) * 32;
    const _Float16* xs = xbase + (size_t)(16 * k) * DIN + kk + aw_col;
    const _Float16* ws = wbase + (size_t)k * NOUT * DIN + kk + aw_col;
    _Float16* la = AB + buf * 4096 + (wave * 32) * 32;       // wave-uniform LDS base
    _Float16* lb = AB + 8192 + buf * 4096 + (wave * 32) * 32;
#pragma unroll
    for (int c = 0; c < 2; ++c) {
      size_t roff = (size_t)(wave * 32 + c * 16 + aw_row) * DIN;
      gload16(xs + roff, la + c * 16 * 32);
      gload16(ws + roff, lb + c * 16 * 32);
    }
  };

  stage(0, 0);
  for (int t = 0; t < NTILES; ++t) {
    int buf = t & 1;
    if (t + 1 < NTILES) {
      stage(t + 1, buf ^ 1);
      asm volatile("s_waitcnt vmcnt(4)" ::: "memory");   // tile t's 4 loads done; t+1's stay in flight
    } else {
      asm volatile("s_waitcnt vmcnt(0)" ::: "memory");
    }
    __builtin_amdgcn_s_barrier();
    __builtin_amdgcn_sched_barrier(0);                   // pin ds_reads below the barrier
    const _Float16* la = AB + buf * 4096;
    const _Float16* lb = AB + 8192 + buf * 4096;
    half8 a[4], b[4];
#pragma unroll
    for (int i = 0; i < 4; ++i) {
      a[i] = *(const half8*)(la + (wm + i * 16 + fr) * 32 + fko);
      b[i] = *(const half8*)(lb + (wn + i * 16 + fr) * 32 + fko);
    }
#pragma unroll
    for (int i = 0; i < 4; ++i)
#pragma unroll
      for (int j = 0; j < 4; ++j)
        acc[i][j] = __builtin_amdgcn_mfma_f32_16x16x32_f16(a[i], b[j], acc[i][j], 0, 0, 0);
    __builtin_amdgcn_sched_barrier(0);                   // pin MFMA/ds_reads above the barrier
    __builtin_amdgcn_s_barrier();                        // buf free for overwrite next iter
  }

  // epilogue: add masked bias, store f32
  const float* b0 = bias;
  const float* b1 = bias + NOUT;
  const float* b2 = bias + 2 * NOUT;
#pragma unroll
  for (int j = 0; j < 4; ++j) {
    int gcol = bcol + wn + j * 16 + fr;
    float bb0 = b0[gcol], bb1 = b1[gcol], bb2 = b2[gcol];
#pragma unroll
    for (int i = 0; i < 4; ++i) {
#pragma unroll
      for (int q = 0; q < 4; ++q) {
        int grow = brow + wm + i * 16 + (lane >> 4) * 4 + q;
        int l = grow >> 4;                      // B == 16
        float bs = bb1 + (l > 0 ? bb0 : 0.f) + (l < L_SEQ - 1 ? bb2 : 0.f);
        g[(size_t)grow * NOUT + gcol] = acc[i][j][q] + bs;
      }
    }
  }
}

// ---------------- fo-pool: chunked linear scan (2 kernels) ----------------
__global__ __launch_bounds__(256) void pool_phase1(const float* __restrict__ g,
                                                   float* __restrict__ Aarr, float* __restrict__ Bvarr,
                                                   int rev) {
  int gid = blockIdx.x * 256 + threadIdx.x;       // 32*8192
  int q = gid >> 13, idx = gid & 8191;
  int b = idx >> 9, j = idx & 511;
  const float* gf = g + (size_t)b * NOUT + j;
  float A = 1.f, Bv = 0.f;
  int l0 = q * 64;
#pragma unroll 4
  for (int t = 0; t < 64; ++t) {
    int l = rev ? (l0 + 63 - t) : (l0 + t);
    size_t off = (size_t)l * (BATCH * NOUT);
    float f = sigm(gf[off]);
    float z = tanh_f(gf[off + 1024]);
    Bv = f * z + (1.f - f) * Bv;
    A *= (1.f - f);
  }
  Aarr[gid] = A;
  Bvarr[gid] = Bv;
}

__global__ __launch_bounds__(256) void pool_phase3(const float* __restrict__ g,
                                                   const float* __restrict__ Aarr,
                                                   const float* __restrict__ Bvarr,
                                                   float* __restrict__ out,
                                                   float* __restrict__ lh, float* __restrict__ lc,
                                                   int rev) {
  int gid = blockIdx.x * 256 + threadIdx.x;       // 32*8192
  int q = gid >> 13, idx = gid & 8191;
  int b = idx >> 9, j = idx & 511;
  const float* gf = g + (size_t)b * NOUT + j;
  // compose carry-in from chunk summaries (replaces old phase2 kernel)
  float c = 0.f;
  if (!rev) {
    for (int s = 0; s < q; ++s) {
      size_t o = (size_t)s * 8192 + idx;
      c = Aarr[o] * c + Bvarr[o];
    }
  } else {
    for (int s = 31; s > q; --s) {
      size_t o = (size_t)s * 8192 + idx;
      c = Aarr[o] * c + Bvarr[o];
    }
  }
  int l0 = q * 64;
#pragma unroll 2
  for (int t = 0; t < 64; ++t) {
    int l = rev ? (l0 + 63 - t) : (l0 + t);
    size_t off = (size_t)l * (BATCH * NOUT);
    float f = sigm(gf[off]);
    float o = sigm(gf[off + 512]);
    float z = tanh_f(gf[off + 1024]);
    c = f * z + (1.f - f) * c;
    float h = c * o;
    out[(size_t)(l * BATCH + b) * 1024 + rev * 512 + j] = h;
    if (l == L_SEQ - 1) {
      lh[b * 1024 + rev * 512 + j] = h;
      lc[b * 1024 + rev * 512 + j] = c;
    }
  }
}

// ---------------- launch ----------------
extern "C" void kernel_launch(void* const* d_in, const int* in_sizes, int n_in,
                              void* d_out, int out_size, void* d_ws, size_t ws_size,
                              hipStream_t stream) {
  const float* x    = (const float*)d_in[0];
  const float* fwdW = (const float*)d_in[2];
  const float* fwdb = (const float*)d_in[3];
  const float* revW = (const float*)d_in[4];
  const float* revb = (const float*)d_in[5];

  float* out = (float*)d_out;
  float* lh  = out + (size_t)L_SEQ * BATCH * 1024;
  float* lc  = lh + BATCH * 1024;

  char* ws = (char*)d_ws;
  size_t off = 0;
  float* g = (float*)(ws + off);              off += (size_t)MROWS * NOUT * 4;   // 192 MB
  _Float16* xhp = (_Float16*)(ws + off);      off += (size_t)PROWS * DIN * 2;    // 33.6 MB
  _Float16* wTf = (_Float16*)(ws + off);      off += (size_t)3 * NOUT * DIN * 2; // 4.7 MB
  _Float16* wTr = (_Float16*)(ws + off);      off += (size_t)3 * NOUT * DIN * 2;
  float* Aarr  = (float*)(ws + off); off += (size_t)32 * 8192 * 4;
  float* Bvarr = (float*)(ws + off); off += (size_t)32 * 8192 * 4;

  prep_x<<<8200, 256, 0, stream>>>(x, xhp);
  prep_w<<<4608, 256, 0, stream>>>(fwdW, revW, wTf, wTr);

  for (int dir = 0; dir < 2; ++dir) {
    const _Float16* wh = dir ? wTr : wTf;
    const float* bias = dir ? revb : fwdb;
    gemm_gates<<<3072, 256, 0, stream>>>(xhp, wh, bias, g);
    pool_phase1<<<1024, 256, 0, stream>>>(g, Aarr, Bvarr, dir);
    pool_phase3<<<1024, 256, 0, stream>>>(g, Aarr, Bvarr, out, lh, lc, dir);
  }
}

// Round 7
// 553.754 us; speedup vs baseline: 2.0937x; 1.1961x over previous
//
#include <hip/hip_runtime.h>

#define L_SEQ 2048
#define BATCH 16
#define DIN   512
#define NOUT  1536                    // 3*D_OUT
#define MROWS (L_SEQ*BATCH)           // 32768
#define PROWS ((L_SEQ+2)*BATCH)       // 32800 padded rows (one zero l at each end)
#define NTILES 48                     // 3 taps * 16 kk-steps of 32

typedef float    f32x4 __attribute__((ext_vector_type(4)));
typedef _Float16 half8 __attribute__((ext_vector_type(8)));

static __device__ __forceinline__ float sigm(float x) { return 1.f / (1.f + __expf(-x)); }
static __device__ __forceinline__ float tanh_f(float x) {
  float ax = fabsf(x);
  float t = __expf(-2.f * ax);
  float r = (1.f - t) / (1.f + t);
  return x < 0.f ? -r : r;
}

// ---------------- prep: pad + fp16 convert of x ----------------
__global__ __launch_bounds__(256) void prep_x(const float* __restrict__ x,
                                              _Float16* __restrict__ xh) {
  int gid = blockIdx.x * 256 + threadIdx.x;       // 32800*64 = 2,099,200 threads
  int pr = gid >> 6, seg = gid & 63;
  int l = (pr >> 4) - 1;
  half8 h = (half8)0;
  if (l >= 0 && l < L_SEQ) {
    const float* src = x + (size_t)(pr - 16) * DIN + seg * 8;
#pragma unroll
    for (int i = 0; i < 8; ++i) h[i] = (_Float16)src[i];
  }
  *(half8*)(xh + (size_t)gid * 8) = h;
}

// ---------------- prep: transpose W [k][d][e] -> wT [k][e][d], fp16 ----------------
__global__ __launch_bounds__(256) void prep_w(const float* __restrict__ Wf, const float* __restrict__ Wr,
                                              _Float16* __restrict__ wTf, _Float16* __restrict__ wTr) {
  __shared__ float tile[32][33];
  int bid = blockIdx.x;                 // 2 dirs * 3 k * 16 dtiles * 48 etiles = 4608
  int dir = bid & 1; bid >>= 1;
  int et = bid % 48; bid /= 48;
  int dt = bid % 16; int k = bid / 16;
  const float* W = dir ? Wr : Wf;
  _Float16* th = dir ? wTr : wTf;
  int tx = threadIdx.x & 31, ty = threadIdx.x >> 5;
  int d0 = dt * 32, e0 = et * 32;
  const float* Wk = W + (size_t)k * DIN * NOUT;
#pragma unroll
  for (int r = 0; r < 4; ++r)
    tile[ty + r * 8][tx] = Wk[(size_t)(d0 + ty + r * 8) * NOUT + e0 + tx];
  __syncthreads();
#pragma unroll
  for (int r = 0; r < 4; ++r) {
    int e = e0 + ty + r * 8;
    size_t o = (size_t)k * NOUT * DIN + (size_t)e * DIN + d0 + tx;
    th[o] = (_Float16)tile[tx][ty + r * 8];
  }
}

// ---------------- gates GEMM: 2-deep counted-vmcnt pipeline, fp16 out ----------------
static __device__ __forceinline__ void gload16(const void* g, void* l) {
  __builtin_amdgcn_global_load_lds((const __attribute__((address_space(1))) void*)g,
                                   (__attribute__((address_space(3))) void*)l, 16, 0, 0);
}

__global__ __launch_bounds__(256) void gemm_gates(
    const _Float16* __restrict__ xh,        // [PROWS][512]
    const _Float16* __restrict__ wTh,       // [3][1536][512]
    const float* __restrict__ bias,         // [3][1536]
    _Float16* __restrict__ g)               // [32768][1536] fp16
{
  // LDS: A buf0 @0, A buf1 @4096, B buf0 @8192, B buf1 @12288 (half elems) = 32 KB
  __shared__ _Float16 AB[4 * 4096];
  const int tid = threadIdx.x;
  const int wave = tid >> 6, lane = tid & 63;
  // L2-locality remap: each XCD gets 32 mt x 12 nt; nt is INNER so 12
  // consecutive same-XCD blocks reuse one x panel (133 KB, L2-hot).
  int bid = blockIdx.x;                                    // 3072 = 8 XCD * 384
  const int xcd = bid & 7, t0 = bid >> 3;                  // t0: 0..383
  const int mt = xcd * 32 + t0 / 12, nt = t0 % 12;
  const int brow = mt * 128, bcol = nt * 128;

  const int aw_row = lane >> 2;
  const int aw_col = ((lane & 3) ^ ((lane >> 3) & 3)) * 8;   // pre-swizzled global source

  const _Float16* xbase = xh + (size_t)brow * DIN;           // tap k adds 16*k rows
  const _Float16* wbase = wTh + (size_t)bcol * DIN;          // tap k adds k*NOUT*DIN

  f32x4 acc[4][4];
#pragma unroll
  for (int i = 0; i < 4; ++i)
#pragma unroll
    for (int j = 0; j < 4; ++j) acc[i][j] = (f32x4)(0.f);

  const int wm = (wave >> 1) * 64, wn = (wave & 1) * 64;
  const int fr = lane & 15;
  const int fko = (((lane >> 4) ^ ((fr >> 1) & 3))) * 8;     // XOR-swizzled read slot

  auto stage = [&](int t, int buf) {
    int k = t >> 4, kk = (t & 15) * 32;
    const _Float16* xs = xbase + (size_t)(16 * k) * DIN + kk + aw_col;
    const _Float16* ws = wbase + (size_t)k * NOUT * DIN + kk + aw_col;
    _Float16* la = AB + buf * 4096 + (wave * 32) * 32;       // wave-uniform LDS base
    _Float16* lb = AB + 8192 + buf * 4096 + (wave * 32) * 32;
#pragma unroll
    for (int c = 0; c < 2; ++c) {
      size_t roff = (size_t)(wave * 32 + c * 16 + aw_row) * DIN;
      gload16(xs + roff, la + c * 16 * 32);
      gload16(ws + roff, lb + c * 16 * 32);
    }
  };

  stage(0, 0);
  for (int t = 0; t < NTILES; ++t) {
    int buf = t & 1;
    if (t + 1 < NTILES) {
      stage(t + 1, buf ^ 1);
      asm volatile("s_waitcnt vmcnt(4)" ::: "memory");   // tile t ready; t+1 stays in flight
    } else {
      asm volatile("s_waitcnt vmcnt(0)" ::: "memory");
    }
    __builtin_amdgcn_s_barrier();
    __builtin_amdgcn_sched_barrier(0);
    const _Float16* la = AB + buf * 4096;
    const _Float16* lb = AB + 8192 + buf * 4096;
    half8 a[4], b[4];
#pragma unroll
    for (int i = 0; i < 4; ++i) {
      a[i] = *(const half8*)(la + (wm + i * 16 + fr) * 32 + fko);
      b[i] = *(const half8*)(lb + (wn + i * 16 + fr) * 32 + fko);
    }
#pragma unroll
    for (int i = 0; i < 4; ++i)
#pragma unroll
      for (int j = 0; j < 4; ++j)
        acc[i][j] = __builtin_amdgcn_mfma_f32_16x16x32_f16(a[i], b[j], acc[i][j], 0, 0, 0);
    __builtin_amdgcn_sched_barrier(0);
    __builtin_amdgcn_s_barrier();
  }

  // epilogue: add masked bias, store fp16
  const float* b0 = bias;
  const float* b1 = bias + NOUT;
  const float* b2 = bias + 2 * NOUT;
#pragma unroll
  for (int j = 0; j < 4; ++j) {
    int gcol = bcol + wn + j * 16 + fr;
    float bb0 = b0[gcol], bb1 = b1[gcol], bb2 = b2[gcol];
#pragma unroll
    for (int i = 0; i < 4; ++i) {
#pragma unroll
      for (int q = 0; q < 4; ++q) {
        int grow = brow + wm + i * 16 + (lane >> 4) * 4 + q;
        int l = grow >> 4;                      // B == 16
        float bs = bb1 + (l > 0 ? bb0 : 0.f) + (l < L_SEQ - 1 ? bb2 : 0.f);
        g[(size_t)grow * NOUT + gcol] = (_Float16)(acc[i][j][q] + bs);
      }
    }
  }
}

// ---------------- fo-pool: chunked linear scan (2 kernels) ----------------
__global__ __launch_bounds__(256) void pool_phase1(const _Float16* __restrict__ g,
                                                   float* __restrict__ Aarr, float* __restrict__ Bvarr,
                                                   int rev) {
  int gid = blockIdx.x * 256 + threadIdx.x;       // 32*8192
  int q = gid >> 13, idx = gid & 8191;
  int b = idx >> 9, j = idx & 511;
  const _Float16* gf = g + (size_t)b * NOUT + j;
  float A = 1.f, Bv = 0.f;
  int l0 = q * 64;
#pragma unroll 4
  for (int t = 0; t < 64; ++t) {
    int l = rev ? (l0 + 63 - t) : (l0 + t);
    size_t off = (size_t)l * (BATCH * NOUT);
    float f = sigm((float)gf[off]);
    float z = tanh_f((float)gf[off + 1024]);
    Bv = f * z + (1.f - f) * Bv;
    A *= (1.f - f);
  }
  Aarr[gid] = A;
  Bvarr[gid] = Bv;
}

__global__ __launch_bounds__(256) void pool_phase3(const _Float16* __restrict__ g,
                                                   const float* __restrict__ Aarr,
                                                   const float* __restrict__ Bvarr,
                                                   float* __restrict__ out,
                                                   float* __restrict__ lh, float* __restrict__ lc,
                                                   int rev) {
  int gid = blockIdx.x * 256 + threadIdx.x;       // 32*8192
  int q = gid >> 13, idx = gid & 8191;
  int b = idx >> 9, j = idx & 511;
  const _Float16* gf = g + (size_t)b * NOUT + j;
  float c = 0.f;
  if (!rev) {
    for (int s = 0; s < q; ++s) {
      size_t o = (size_t)s * 8192 + idx;
      c = Aarr[o] * c + Bvarr[o];
    }
  } else {
    for (int s = 31; s > q; --s) {
      size_t o = (size_t)s * 8192 + idx;
      c = Aarr[o] * c + Bvarr[o];
    }
  }
  int l0 = q * 64;
#pragma unroll 2
  for (int t = 0; t < 64; ++t) {
    int l = rev ? (l0 + 63 - t) : (l0 + t);
    size_t off = (size_t)l * (BATCH * NOUT);
    float f = sigm((float)gf[off]);
    float o = sigm((float)gf[off + 512]);
    float z = tanh_f((float)gf[off + 1024]);
    c = f * z + (1.f - f) * c;
    float h = c * o;
    out[(size_t)(l * BATCH + b) * 1024 + rev * 512 + j] = h;
    if (l == L_SEQ - 1) {
      lh[b * 1024 + rev * 512 + j] = h;
      lc[b * 1024 + rev * 512 + j] = c;
    }
  }
}

// ---------------- launch ----------------
extern "C" void kernel_launch(void* const* d_in, const int* in_sizes, int n_in,
                              void* d_out, int out_size, void* d_ws, size_t ws_size,
                              hipStream_t stream) {
  const float* x    = (const float*)d_in[0];
  const float* fwdW = (const float*)d_in[2];
  const float* fwdb = (const float*)d_in[3];
  const float* revW = (const float*)d_in[4];
  const float* revb = (const float*)d_in[5];

  float* out = (float*)d_out;
  float* lh  = out + (size_t)L_SEQ * BATCH * 1024;
  float* lc  = lh + BATCH * 1024;

  char* ws = (char*)d_ws;
  size_t off = 0;
  _Float16* g = (_Float16*)(ws + off);        off += (size_t)MROWS * NOUT * 2;   // 96 MB fp16
  _Float16* xhp = (_Float16*)(ws + off);      off += (size_t)PROWS * DIN * 2;    // 33.6 MB
  _Float16* wTf = (_Float16*)(ws + off);      off += (size_t)3 * NOUT * DIN * 2; // 4.7 MB
  _Float16* wTr = (_Float16*)(ws + off);      off += (size_t)3 * NOUT * DIN * 2;
  float* Aarr  = (float*)(ws + off); off += (size_t)32 * 8192 * 4;
  float* Bvarr = (float*)(ws + off); off += (size_t)32 * 8192 * 4;

  prep_x<<<8200, 256, 0, stream>>>(x, xhp);
  prep_w<<<4608, 256, 0, stream>>>(fwdW, revW, wTf, wTr);

  for (int dir = 0; dir < 2; ++dir) {
    const _Float16* wh = dir ? wTr : wTf;
    const float* bias = dir ? revb : fwdb;
    gemm_gates<<<3072, 256, 0, stream>>>(xhp, wh, bias, g);
    pool_phase1<<<1024, 256, 0, stream>>>(g, Aarr, Bvarr, dir);
    pool_phase3<<<1024, 256, 0, stream>>>(g, Aarr, Bvarr, out, lh, lc, dir);
  }
}

// Round 8
// 463.711 us; speedup vs baseline: 2.5003x; 1.1942x over previous
//
#include <hip/hip_runtime.h>

#define L_SEQ 2048
#define BATCH 16
#define DIN   512
#define NOUT  1536                    // 3*D_OUT per direction
#define GSTRIDE 3072                  // 2 dirs * 1536, g row stride
#define MROWS (L_SEQ*BATCH)           // 32768
#define PROWS ((L_SEQ+2)*BATCH)       // 32800 padded rows
#define NTILES 48                     // 3 taps * 16 kk-steps of 32

typedef float    f32x4 __attribute__((ext_vector_type(4)));
typedef _Float16 half8 __attribute__((ext_vector_type(8)));

static __device__ __forceinline__ float sigm(float x) { return 1.f / (1.f + __expf(-x)); }
static __device__ __forceinline__ float tanh_f(float x) {
  float ax = fabsf(x);
  float t = __expf(-2.f * ax);
  float r = (1.f - t) / (1.f + t);
  return x < 0.f ? -r : r;
}

// ---------------- prep: pad + fp16 convert of x ----------------
__global__ __launch_bounds__(256) void prep_x(const float* __restrict__ x,
                                              _Float16* __restrict__ xh) {
  int gid = blockIdx.x * 256 + threadIdx.x;       // 32800*64
  int pr = gid >> 6, seg = gid & 63;
  int l = (pr >> 4) - 1;
  half8 h = (half8)0;
  if (l >= 0 && l < L_SEQ) {
    const float* src = x + (size_t)(pr - 16) * DIN + seg * 8;
#pragma unroll
    for (int i = 0; i < 8; ++i) h[i] = (_Float16)src[i];
  }
  *(half8*)(xh + (size_t)gid * 8) = h;
}

// ---------------- prep: transpose W [k][d][e] -> wT [k][e][d], fp16 ----------------
__global__ __launch_bounds__(256) void prep_w(const float* __restrict__ Wf, const float* __restrict__ Wr,
                                              _Float16* __restrict__ wTf, _Float16* __restrict__ wTr) {
  __shared__ float tile[32][33];
  int bid = blockIdx.x;                 // 2 dirs * 3 k * 16 dtiles * 48 etiles = 4608
  int dir = bid & 1; bid >>= 1;
  int et = bid % 48; bid /= 48;
  int dt = bid % 16; int k = bid / 16;
  const float* W = dir ? Wr : Wf;
  _Float16* th = dir ? wTr : wTf;
  int tx = threadIdx.x & 31, ty = threadIdx.x >> 5;
  int d0 = dt * 32, e0 = et * 32;
  const float* Wk = W + (size_t)k * DIN * NOUT;
#pragma unroll
  for (int r = 0; r < 4; ++r)
    tile[ty + r * 8][tx] = Wk[(size_t)(d0 + ty + r * 8) * NOUT + e0 + tx];
  __syncthreads();
#pragma unroll
  for (int r = 0; r < 4; ++r) {
    int e = e0 + ty + r * 8;
    size_t o = (size_t)k * NOUT * DIN + (size_t)e * DIN + d0 + tx;
    th[o] = (_Float16)tile[tx][ty + r * 8];
  }
}

// ---------------- gates GEMM: 256x128 tile, both dirs, 2-deep pipeline ----------------
static __device__ __forceinline__ void gload16(const void* g, void* l) {
  __builtin_amdgcn_global_load_lds((const __attribute__((address_space(1))) void*)g,
                                   (__attribute__((address_space(3))) void*)l, 16, 0, 0);
}

__global__ __launch_bounds__(256, 2) void gemm_gates(
    const _Float16* __restrict__ xh,        // [PROWS][512]
    const _Float16* __restrict__ wTf,       // [3][1536][512]
    const _Float16* __restrict__ wTr,       // [3][1536][512]
    const float* __restrict__ biasf,        // [3][1536]
    const float* __restrict__ biasr,        // [3][1536]
    _Float16* __restrict__ g)               // [32768][3072] fp16
{
  // LDS halfs: A [2][256][32] @0 (32KB), B [2][128][32] @16384 (16KB) = 48KB
  __shared__ _Float16 AB[24576];
  const int tid = threadIdx.x;
  const int wave = tid >> 6, lane = tid & 63;
  // L2 remap: 3072 = 8 XCD * 384; per XCD 16 mt-groups * 24 nt (nt inner -> x panel reuse)
  int bid = blockIdx.x;
  const int xcd = bid & 7, t0 = bid >> 3;
  const int mt = xcd * 16 + t0 / 24, nt = t0 % 24;
  const int dir = nt / 12, ntd = nt % 12;
  const int brow = mt * 256, bcol = ntd * 128;

  const _Float16* wTh = dir ? wTr : wTf;
  const float* bias   = dir ? biasr : biasf;

  // staging: thread covers (row_rel = c*64 + (tid>>2), slot = tid&3), source slot XOR-swizzled
  const int aw_col = ((tid & 3) ^ ((tid >> 3) & 3)) * 8;

  const _Float16* xbase = xh + (size_t)brow * DIN;
  const _Float16* wbase = wTh + (size_t)bcol * DIN;

  f32x4 acc[8][4];
#pragma unroll
  for (int i = 0; i < 8; ++i)
#pragma unroll
    for (int j = 0; j < 4; ++j) acc[i][j] = (f32x4)(0.f);

  const int wm = (wave >> 1) * 128, wn = (wave & 1) * 64;
  const int fr = lane & 15;
  const int fko = (((lane >> 4) ^ ((fr >> 1) & 3))) * 8;     // XOR-swizzled read slot

  auto stage = [&](int t, int buf) {
    int k = t >> 4, kk = (t & 15) * 32;
    const _Float16* xs = xbase + (size_t)(16 * k) * DIN + kk + aw_col;
    const _Float16* ws = wbase + (size_t)k * NOUT * DIN + kk + aw_col;
    // A: 4 rounds of 64 rows
#pragma unroll
    for (int c = 0; c < 4; ++c) {
      int row = c * 64 + (tid >> 2);
      gload16(xs + (size_t)row * DIN, AB + buf * 8192 + (c * 64 + (wave * 16)) * 32);
    }
    // B: 2 rounds of 64 rows
#pragma unroll
    for (int c = 0; c < 2; ++c) {
      int row = c * 64 + (tid >> 2);
      gload16(ws + (size_t)row * DIN, AB + 16384 + buf * 4096 + (c * 64 + (wave * 16)) * 32);
    }
  };

  stage(0, 0);
  for (int t = 0; t < NTILES; ++t) {
    int buf = t & 1;
    if (t + 1 < NTILES) {
      stage(t + 1, buf ^ 1);
      asm volatile("s_waitcnt vmcnt(6)" ::: "memory");   // tile t's 6 loads done; t+1's in flight
    } else {
      asm volatile("s_waitcnt vmcnt(0)" ::: "memory");
    }
    __builtin_amdgcn_s_barrier();
    __builtin_amdgcn_sched_barrier(0);
    const _Float16* la = AB + buf * 8192;
    const _Float16* lb = AB + 16384 + buf * 4096;
    half8 a[8], b[4];
#pragma unroll
    for (int i = 0; i < 8; ++i)
      a[i] = *(const half8*)(la + (wm + i * 16 + fr) * 32 + fko);
#pragma unroll
    for (int j = 0; j < 4; ++j)
      b[j] = *(const half8*)(lb + (wn + j * 16 + fr) * 32 + fko);
    __builtin_amdgcn_s_setprio(1);
#pragma unroll
    for (int i = 0; i < 8; ++i)
#pragma unroll
      for (int j = 0; j < 4; ++j)
        acc[i][j] = __builtin_amdgcn_mfma_f32_16x16x32_f16(a[i], b[j], acc[i][j], 0, 0, 0);
    __builtin_amdgcn_s_setprio(0);
    __builtin_amdgcn_sched_barrier(0);
    __builtin_amdgcn_s_barrier();
  }

  // epilogue: masked bias, store fp16 into [row][dir*1536 + col]
  const float* b0 = bias;
  const float* b1 = bias + NOUT;
  const float* b2 = bias + 2 * NOUT;
#pragma unroll
  for (int j = 0; j < 4; ++j) {
    int col = bcol + wn + j * 16 + fr;                 // 0..1535 within dir
    float bb0 = b0[col], bb1 = b1[col], bb2 = b2[col];
    size_t gcol = (size_t)dir * NOUT + col;
#pragma unroll
    for (int i = 0; i < 8; ++i) {
#pragma unroll
      for (int q = 0; q < 4; ++q) {
        int grow = brow + wm + i * 16 + (lane >> 4) * 4 + q;
        int l = grow >> 4;                             // BATCH == 16
        float bs = bb1 + (l > 0 ? bb0 : 0.f) + (l < L_SEQ - 1 ? bb2 : 0.f);
        g[(size_t)grow * GSTRIDE + gcol] = (_Float16)(acc[i][j][q] + bs);
      }
    }
  }
}

// ---------------- fo-pool: chunked linear scan, both dirs ----------------
__global__ __launch_bounds__(256) void pool_phase1(const _Float16* __restrict__ g,
                                                   float* __restrict__ Aarr, float* __restrict__ Bvarr) {
  int gid = blockIdx.x * 256 + threadIdx.x;       // 2*32*8192 = 524288
  int rev = gid >> 18;
  int idx = gid & 262143;
  int q = idx >> 13, sidx = idx & 8191;
  int b = sidx >> 9, j = sidx & 511;
  const _Float16* gf = g + (size_t)b * GSTRIDE + (size_t)rev * NOUT + j;
  float A = 1.f, Bv = 0.f;
  int l0 = q * 64;
#pragma unroll 4
  for (int t = 0; t < 64; ++t) {
    int l = rev ? (l0 + 63 - t) : (l0 + t);
    size_t off = (size_t)l * (BATCH * GSTRIDE);
    float f = sigm((float)gf[off]);
    float z = tanh_f((float)gf[off + 1024]);
    Bv = f * z + (1.f - f) * Bv;
    A *= (1.f - f);
  }
  Aarr[gid] = A;
  Bvarr[gid] = Bv;
}

__global__ __launch_bounds__(256) void pool_phase3(const _Float16* __restrict__ g,
                                                   const float* __restrict__ Aarr,
                                                   const float* __restrict__ Bvarr,
                                                   float* __restrict__ out,
                                                   float* __restrict__ lh, float* __restrict__ lc) {
  int gid = blockIdx.x * 256 + threadIdx.x;       // 524288
  int rev = gid >> 18;
  int idx = gid & 262143;
  int q = idx >> 13, sidx = idx & 8191;
  int b = sidx >> 9, j = sidx & 511;
  const _Float16* gf = g + (size_t)b * GSTRIDE + (size_t)rev * NOUT + j;
  const float* Ad = Aarr + (size_t)rev * 262144;
  const float* Bd = Bvarr + (size_t)rev * 262144;
  float c = 0.f;
  if (!rev) {
    for (int s = 0; s < q; ++s) {
      size_t o = (size_t)s * 8192 + sidx;
      c = Ad[o] * c + Bd[o];
    }
  } else {
    for (int s = 31; s > q; --s) {
      size_t o = (size_t)s * 8192 + sidx;
      c = Ad[o] * c + Bd[o];
    }
  }
  int l0 = q * 64;
#pragma unroll 2
  for (int t = 0; t < 64; ++t) {
    int l = rev ? (l0 + 63 - t) : (l0 + t);
    size_t off = (size_t)l * (BATCH * GSTRIDE);
    float f = sigm((float)gf[off]);
    float o = sigm((float)gf[off + 512]);
    float z = tanh_f((float)gf[off + 1024]);
    c = f * z + (1.f - f) * c;
    float h = c * o;
    out[(size_t)(l * BATCH + b) * 1024 + rev * 512 + j] = h;
    if (l == L_SEQ - 1) {
      lh[b * 1024 + rev * 512 + j] = h;
      lc[b * 1024 + rev * 512 + j] = c;
    }
  }
}

// ---------------- launch ----------------
extern "C" void kernel_launch(void* const* d_in, const int* in_sizes, int n_in,
                              void* d_out, int out_size, void* d_ws, size_t ws_size,
                              hipStream_t stream) {
  const float* x    = (const float*)d_in[0];
  const float* fwdW = (const float*)d_in[2];
  const float* fwdb = (const float*)d_in[3];
  const float* revW = (const float*)d_in[4];
  const float* revb = (const float*)d_in[5];

  float* out = (float*)d_out;
  float* lh  = out + (size_t)L_SEQ * BATCH * 1024;
  float* lc  = lh + BATCH * 1024;

  char* ws = (char*)d_ws;
  size_t off = 0;
  _Float16* g = (_Float16*)(ws + off);        off += (size_t)MROWS * GSTRIDE * 2; // 192 MB fp16
  _Float16* xhp = (_Float16*)(ws + off);      off += (size_t)PROWS * DIN * 2;     // 33.6 MB
  _Float16* wTf = (_Float16*)(ws + off);      off += (size_t)3 * NOUT * DIN * 2;  // 4.7 MB
  _Float16* wTr = (_Float16*)(ws + off);      off += (size_t)3 * NOUT * DIN * 2;
  float* Aarr  = (float*)(ws + off); off += (size_t)2 * 32 * 8192 * 4;
  float* Bvarr = (float*)(ws + off); off += (size_t)2 * 32 * 8192 * 4;

  prep_x<<<8200, 256, 0, stream>>>(x, xhp);
  prep_w<<<4608, 256, 0, stream>>>(fwdW, revW, wTf, wTr);

  gemm_gates<<<3072, 256, 0, stream>>>(xhp, wTf, wTr, fwdb, revb, g);
  pool_phase1<<<2048, 256, 0, stream>>>(g, Aarr, Bvarr);
  pool_phase3<<<2048, 256, 0, stream>>>(g, Aarr, Bvarr, out, lh, lc);
}